// Round 14
// baseline (9502.237 us; speedup 1.0000x reference)
//
#include <hip/hip_runtime.h>

// FusedLoRAQKV on MI355X (gfx950).
// Y_p = X @ (W_p + 2 * B_p @ A_p)^T  for p in {Q,K,V}
//
// Pipeline:
//   1. cvt_x:    X fp32 -> bf16
//   2. merge_w3: W' = bf16(W + 2*B@A), all three projections, one launch
//   3. gemm:     256x256 tile, BK=32, 8 waves, mfma_f32_16x16x32_bf16,
//                64 KiB LDS -> TWO blocks/CU (was 128KiB -> 1 block: all
//                waves in one barrier group, no cross-block MFMA||LDS
//                overlap -- the m114 mechanism needs independent blocks).
//                VGPR 128 (512-pool: 4 waves/SIMD) + acc in 128 AGPRs
//                (separate 512 pool) -> occupancy gated only by LDS.
//                One barrier per K-tile: {BAR; 12 reads; 4 stages; 32 MFMA;
//                vmcnt(0)}. Swizzle for 64B rows: chunk ^= (row>>1)&3.
//                LDS-transposed epilogue (R13 win) adapted to 64KiB.

typedef unsigned short u16;
typedef __attribute__((ext_vector_type(4))) float  f32x4;
typedef __attribute__((ext_vector_type(8))) __bf16 bf16x8;
typedef __attribute__((ext_vector_type(8))) short  s16x8;

#define MDIM 8192
#define NDIM 4096
#define KDIM 4096

__device__ __forceinline__ u16 f2bf(float f) {
    union { float f; unsigned int u; } v;
    v.f = f;
    unsigned int r = v.u + 0x7FFFu + ((v.u >> 16) & 1u);  // RNE
    return (u16)(r >> 16);
}

// ---------------- Kernel 1: X fp32 -> bf16 ----------------
__global__ void __launch_bounds__(256) cvt_x_kernel(const float* __restrict__ X,
                                                    u16* __restrict__ Xb, int nvec8) {
    int stride = gridDim.x * blockDim.x;
    for (int i = blockIdx.x * blockDim.x + threadIdx.x; i < nvec8; i += stride) {
        f32x4 x0 = ((const f32x4*)X)[2 * i];
        f32x4 x1 = ((const f32x4*)X)[2 * i + 1];
        s16x8 o;
        o[0] = (short)f2bf(x0[0]); o[1] = (short)f2bf(x0[1]);
        o[2] = (short)f2bf(x0[2]); o[3] = (short)f2bf(x0[3]);
        o[4] = (short)f2bf(x1[0]); o[5] = (short)f2bf(x1[1]);
        o[6] = (short)f2bf(x1[2]); o[7] = (short)f2bf(x1[3]);
        ((s16x8*)Xb)[i] = o;
    }
}

// ---------------- Kernel 2: W' = bf16(W + 2*B@A), z = projection ----------------
__global__ void __launch_bounds__(256) merge_w3_kernel(const float* __restrict__ QW,
                                                       const float* __restrict__ QA,
                                                       const float* __restrict__ QB,
                                                       const float* __restrict__ KW,
                                                       const float* __restrict__ KA,
                                                       const float* __restrict__ KB,
                                                       const float* __restrict__ VW,
                                                       const float* __restrict__ VA,
                                                       const float* __restrict__ VB,
                                                       u16* __restrict__ WbAll) {
    const int z = blockIdx.z;
    const float* W  = (z == 0) ? QW : (z == 1) ? KW : VW;
    const float* A  = (z == 0) ? QA : (z == 1) ? KA : VA;
    const float* Bm = (z == 0) ? QB : (z == 1) ? KB : VB;
    u16* Wb = WbAll + (size_t)z * NDIM * KDIM;

    __shared__ float As[16][64];
    const int t  = threadIdx.x;
    const int hb = blockIdx.x * 64;
    const int nb = blockIdx.y * 128;

    {   // stage A[16][hb:hb+64]
        int r = t >> 4, c = (t & 15) * 4;
        *(f32x4*)&As[r][c] = *(const f32x4*)&A[r * 4096 + hb + c];
    }
    __syncthreads();

    const int hl = (t & 7) * 8;
    const int n0 = nb + (t >> 3) * 4;

    float bv[4][16];
    float s[4][8];
#pragma unroll
    for (int i = 0; i < 4; i++) {
        const float* br = &Bm[(size_t)(n0 + i) * 16];
#pragma unroll
        for (int r = 0; r < 16; r++) bv[i][r] = 2.0f * br[r];
        f32x4 w0 = *(const f32x4*)&W[(size_t)(n0 + i) * 4096 + hb + hl];
        f32x4 w1 = *(const f32x4*)&W[(size_t)(n0 + i) * 4096 + hb + hl + 4];
        s[i][0] = w0[0]; s[i][1] = w0[1]; s[i][2] = w0[2]; s[i][3] = w0[3];
        s[i][4] = w1[0]; s[i][5] = w1[1]; s[i][6] = w1[2]; s[i][7] = w1[3];
    }
#pragma unroll
    for (int r = 0; r < 16; r++) {
        f32x4 a0 = *(const f32x4*)&As[r][hl];
        f32x4 a1 = *(const f32x4*)&As[r][hl + 4];
#pragma unroll
        for (int i = 0; i < 4; i++) {
            s[i][0] += bv[i][r] * a0[0]; s[i][1] += bv[i][r] * a0[1];
            s[i][2] += bv[i][r] * a0[2]; s[i][3] += bv[i][r] * a0[3];
            s[i][4] += bv[i][r] * a1[0]; s[i][5] += bv[i][r] * a1[1];
            s[i][6] += bv[i][r] * a1[2]; s[i][7] += bv[i][r] * a1[3];
        }
    }
#pragma unroll
    for (int i = 0; i < 4; i++) {
        s16x8 o;
#pragma unroll
        for (int j = 0; j < 8; j++) o[j] = (short)f2bf(s[i][j]);
        *(s16x8*)&Wb[(size_t)(n0 + i) * 4096 + hb + hl] = o;
    }
}

// ---------------- Kernel 3: 256x256 GEMM, BK=32, 2 blocks/CU ----------------
// 8 waves (2M x 4N), per-wave 128x64 out, acc[8][4] f32x4 (128 AGPRs).
// LDS 64 KiB: A[2][256][32] + B[2][256][32] bf16 (16 KiB each).
// Swizzle (16B chunks, 4/row): LDS(row,c) = global(row, c ^ ((row>>1)&3)).
//   Read: chunk = lkq ^ ((lr>>1)&3)  [(row>>1)&3 == (lr>>1)&3: wr*128, wn*64,
//   mi*16 all contribute 0 mod 4 after >>1]. Bank check per 16-lane group:
//   slot(row,c) = 4*(row&1) + c mod 8 -> rows 0..7 hit 8 distinct slots,
//   rows 8..15 repeat -> 2-way = free (m136).
//   Stage (linear LDS, 2 instr/operand): thread chunk_id = j*512 + w*64+lane;
//   row = j*128 + w*16 + (lane>>2), src chunk = (lane&3) ^ ((lane>>3)&3).
//
// Phase (ONE barrier per K-tile T, parity p = T&1):
//   BAR; 12 reads (bufs p); STG A(T+1)+B(T+1) -> bufs p^1 (4 instr);
//   32 MFMA; vmcnt(0)
// WAR: bufs p^1 last read in phase T-1 (drained by consuming MFMA before
// that wave reached BAR(T)); stage is after BAR(T) -> >=1 barrier. vmcnt(0)
// drains own 4 stage loads (~1 phase slack); BAR(T+1) publishes all waves'.
// Cross-block overlap: 2 independent blocks/CU slip freely -> one block's
// read/stage window overlaps the other's MFMA window (m114 mechanism).

#define BM 256
#define BN 256

#define BAR() asm volatile("s_barrier" ::: "memory")
#define WAIT_VM(n) asm volatile("s_waitcnt vmcnt(" #n ")" ::: "memory")
#define PRIO(p) __builtin_amdgcn_s_setprio(p)

__global__ void __launch_bounds__(512, 4) gemm8_kernel(const u16* __restrict__ Xb,
                                                       const u16* __restrict__ Wb,
                                                       float* __restrict__ out) {
    extern __shared__ char lds[];

    const int t    = threadIdx.x;
    const int lane = t & 63;
    const int w    = t >> 6;      // wave 0..7
    const int wr   = w >> 2;      // M wave 0..1
    const int wn   = w & 3;       // N wave 0..3
    const int lr   = lane & 15;
    const int lkq  = lane >> 4;

    // Z-sequential XCD-bijective remap (R8): z = orig/512 sequential bands;
    // within z: i = (r&7)*64 + r/8 (bijective, 512 = 8 x 64).
    const int orig = blockIdx.x;
    const int z    = orig >> 9;
    const int r0   = orig & 511;
    const int i_   = (r0 & 7) * 64 + (r0 >> 3);
    const int nT = i_ & 15;
    const int mT = i_ >> 4;
    const int mBase = mT * BM;
    const int nBase = nT * BN;

    const u16* Wp = Wb + (size_t)z * NDIM * KDIM;
    const char* gA = (const char*)Xb + (size_t)mBase * (KDIM * 2);
    const char* gB = (const char*)Wp + (size_t)nBase * (KDIM * 2);

    char* ldsA0 = lds;              // 16 KiB each
    char* ldsA1 = lds + 16384;
    char* ldsB0 = lds + 32768;
    char* ldsB1 = lds + 49152;

    // staging geometry (2 instr per operand tile): j in {0,1}
    const int srcc = (((lane & 3) ^ ((lane >> 3) & 3)) << 4);
    const size_t stgO0 = (size_t)(0 * 128 + w * 16 + (lane >> 2)) * (KDIM * 2) + srcc;
    const size_t stgO1 = (size_t)(1 * 128 + w * 16 + (lane >> 2)) * (KDIM * 2) + srcc;
    const int ldsO0 = (0 * 512 + w * 64 + lane) * 16;
    const int ldsO1 = (1 * 512 + w * 64 + lane) * 16;

#define STG_OP(ldsT, g, kt)                                                       \
  { __builtin_amdgcn_global_load_lds(                                             \
        (const __attribute__((address_space(1))) void*)((g) + stgO0 +             \
            (size_t)(kt) * 64),                                                   \
        (__attribute__((address_space(3))) void*)((ldsT) + ldsO0), 16, 0, 0);     \
    __builtin_amdgcn_global_load_lds(                                             \
        (const __attribute__((address_space(1))) void*)((g) + stgO1 +             \
            (size_t)(kt) * 64),                                                   \
        (__attribute__((address_space(3))) void*)((ldsT) + ldsO1), 16, 0, 0); }

    // fragment reads: row byte stride 64; chunk = lkq ^ ((lr>>1)&3)
    const int csw = ((lkq ^ ((lr >> 1) & 3)) << 4);
    const int rA0 = (wr * 128 + lr) * 64;
    const int rB0 = (wn * 64 + lr) * 64;
#define RD_A(tile, mi) (*(const bf16x8*)((tile) + rA0 + (mi) * 1024 + csw))
#define RD_B(tile, ni) (*(const bf16x8*)((tile) + rB0 + (ni) * 1024 + csw))

    f32x4 acc[8][4] = {};
    bf16x8 a[8], b[4];

// one K-tile phase: BAR; 12 reads (consumption order); stage; 32 MFMA; vmcnt
#define PHASE(pA, pB, STG, VMW)                                                   \
  { BAR();                                                                        \
    a[0] = RD_A(pA, 0); b[0] = RD_B(pB, 0);                                       \
    a[1] = RD_A(pA, 1); b[1] = RD_B(pB, 1);                                       \
    a[2] = RD_A(pA, 2); b[2] = RD_B(pB, 2);                                       \
    a[3] = RD_A(pA, 3); b[3] = RD_B(pB, 3);                                       \
    a[4] = RD_A(pA, 4); a[5] = RD_A(pA, 5);                                       \
    a[6] = RD_A(pA, 6); a[7] = RD_A(pA, 7);                                       \
    STG;                                                                          \
    PRIO(1);                                                                      \
    _Pragma("unroll") for (int mi = 0; mi < 8; ++mi)                              \
    _Pragma("unroll") for (int ni = 0; ni < 4; ++ni)                              \
      acc[mi][ni] = __builtin_amdgcn_mfma_f32_16x16x32_bf16(                      \
          a[mi], b[ni], acc[mi][ni], 0, 0, 0);                                    \
    PRIO(0); VMW; }

    // ---- prologue: stage tile 0 ----
    STG_OP(ldsA0, gA, 0) STG_OP(ldsB0, gB, 0)
    WAIT_VM(0);

    // ---- main loop: 63 iterations (tiles T=2i, 2i+1), stages up to kt=126 ----
    for (int i = 0; i < 63; ++i) {
        const int T = 2 * i;
        PHASE(ldsA0, ldsB0, { STG_OP(ldsA1, gA, T + 1) STG_OP(ldsB1, gB, T + 1) },
              WAIT_VM(0));
        PHASE(ldsA1, ldsB1, { STG_OP(ldsA0, gA, T + 2) STG_OP(ldsB0, gB, T + 2) },
              WAIT_VM(0));
    }
    // ---- peeled tiles 126, 127 ----
    PHASE(ldsA0, ldsB0, { STG_OP(ldsA1, gA, 127) STG_OP(ldsB1, gB, 127) },
          WAIT_VM(0));
    PHASE(ldsA1, ldsB1, , );

    // ---- epilogue: LDS-transpose (64 KiB = f32 [64][256]) + full-line nt stores ----
    BAR();   // all waves' K-loop LDS reads complete -> LDS reusable
    float* C    = out + (size_t)z * MDIM * NDIM;
    float* ldsf = (float*)lds;
#pragma unroll
    for (int r = 0; r < 4; ++r) {
        if (wr == (r >> 1)) {
            // dump rows [r*64, r*64+64) of the 256-row tile
#pragma unroll
            for (int m2 = 0; m2 < 4; ++m2) {
                const int mi = (r & 1) * 4 + m2;
#pragma unroll
                for (int ni = 0; ni < 4; ++ni) {
                    const int lrow = m2 * 16 + lkq * 4;
                    const int col  = wn * 64 + ni * 16 + lr;
                    f32x4 v = acc[mi][ni];
#pragma unroll
                    for (int j = 0; j < 4; ++j)
                        ldsf[(lrow + j) * 256 + col] = v[j];
                }
            }
        }
        BAR();
        // all 8 waves: 8 rows each; 64 lanes x f32x4 = 1KB full-line segments
        const size_t gb = (size_t)(mBase + r * 64) * NDIM + nBase;
#pragma unroll
        for (int rr = 0; rr < 8; ++rr) {
            const int row = w * 8 + rr;
            f32x4 v = *(const f32x4*)&ldsf[row * 256 + lane * 4];
            __builtin_nontemporal_store(v,
                (f32x4*)(C + gb + (size_t)row * NDIM + lane * 4));
        }
        BAR();   // before next round overwrites LDS
    }
}

// ---------------- host launch ----------------
extern "C" void kernel_launch(void* const* d_in, const int* in_sizes, int n_in,
                              void* d_out, int out_size, void* d_ws, size_t ws_size,
                              hipStream_t stream) {
    const float* X  = (const float*)d_in[0];
    const float* QW = (const float*)d_in[1];
    const float* QA = (const float*)d_in[2];
    const float* QB = (const float*)d_in[3];
    const float* KW = (const float*)d_in[4];
    const float* KA = (const float*)d_in[5];
    const float* KB = (const float*)d_in[6];
    const float* VW = (const float*)d_in[7];
    const float* VA = (const float*)d_in[8];
    const float* VB = (const float*)d_in[9];
    float* out = (float*)d_out;

    u16* Xb = (u16*)d_ws;                                        // 64 MiB
    u16* Wb = (u16*)((char*)d_ws + (size_t)MDIM * KDIM * 2);     // 3 x 32 MiB

    (void)hipFuncSetAttribute((const void*)gemm8_kernel,
                              hipFuncAttributeMaxDynamicSharedMemorySize, 65536);

    cvt_x_kernel<<<2048, 256, 0, stream>>>(X, Xb, (MDIM * KDIM) / 8);

    dim3 wgrid(4096 / 64, 4096 / 128, 3);
    merge_w3_kernel<<<wgrid, 256, 0, stream>>>(QW, QA, QB, KW, KA, KB, VW, VA, VB, Wb);

    gemm8_kernel<<<dim3(16 * 32 * 3), dim3(512), 65536, stream>>>(Xb, Wb, out);
}

// Round 16
// 884.624 us; speedup vs baseline: 10.7416x; 10.7416x over previous
//
#include <hip/hip_runtime.h>

// FusedLoRAQKV on MI355X (gfx950).
// Y_p = X @ (W_p + 2 * B_p @ A_p)^T  for p in {Q,K,V}
//
// Pipeline:
//   1. cvt_x:    X fp32 -> bf16
//   2. merge_w3: W' = bf16(W + 2*B@A), all three projections, one launch
//   3. gemm:     256x128 tile, BK=32, FOUR waves (2Mx2N), 48 KiB LDS ->
//                2 independent blocks/CU at 2 waves/SIMD (unified VGPR/AGPR
//                file: 256 regs/wave needed; R14's 4-wave/SIMD cap spilled).
//                Two barrier-independent groups give cross-block MFMA||LDS
//                overlap (m114). One raw barrier per K-tile: {BAR; 12 reads;
//                6 stages; 32 MFMA; vmcnt(0)} -- K-loop raw BARs are safe
//                (ds_reads lgkm-consumed by MFMA pre-BAR; stages vmcnt(0)-
//                drained pre-BAR). EPILOGUE uses __syncthreads(): R15's raw
//                s_barrier after the acc->LDS dump raced (ds_writes have no
//                in-wave consumer -> no compiler lgkm wait -> other waves
//                read stale LDS; fired only at 2 blocks/CU). ISA 8: s_barrier
//                needs s_waitcnt first if data dep.

typedef unsigned short u16;
typedef __attribute__((ext_vector_type(4))) float  f32x4;
typedef __attribute__((ext_vector_type(8))) __bf16 bf16x8;
typedef __attribute__((ext_vector_type(8))) short  s16x8;

#define MDIM 8192
#define NDIM 4096
#define KDIM 4096

__device__ __forceinline__ u16 f2bf(float f) {
    union { float f; unsigned int u; } v;
    v.f = f;
    unsigned int r = v.u + 0x7FFFu + ((v.u >> 16) & 1u);  // RNE
    return (u16)(r >> 16);
}

// ---------------- Kernel 1: X fp32 -> bf16 ----------------
__global__ void __launch_bounds__(256) cvt_x_kernel(const float* __restrict__ X,
                                                    u16* __restrict__ Xb, int nvec8) {
    int stride = gridDim.x * blockDim.x;
    for (int i = blockIdx.x * blockDim.x + threadIdx.x; i < nvec8; i += stride) {
        f32x4 x0 = ((const f32x4*)X)[2 * i];
        f32x4 x1 = ((const f32x4*)X)[2 * i + 1];
        s16x8 o;
        o[0] = (short)f2bf(x0[0]); o[1] = (short)f2bf(x0[1]);
        o[2] = (short)f2bf(x0[2]); o[3] = (short)f2bf(x0[3]);
        o[4] = (short)f2bf(x1[0]); o[5] = (short)f2bf(x1[1]);
        o[6] = (short)f2bf(x1[2]); o[7] = (short)f2bf(x1[3]);
        ((s16x8*)Xb)[i] = o;
    }
}

// ---------------- Kernel 2: W' = bf16(W + 2*B@A), z = projection ----------------
__global__ void __launch_bounds__(256) merge_w3_kernel(const float* __restrict__ QW,
                                                       const float* __restrict__ QA,
                                                       const float* __restrict__ QB,
                                                       const float* __restrict__ KW,
                                                       const float* __restrict__ KA,
                                                       const float* __restrict__ KB,
                                                       const float* __restrict__ VW,
                                                       const float* __restrict__ VA,
                                                       const float* __restrict__ VB,
                                                       u16* __restrict__ WbAll) {
    const int z = blockIdx.z;
    const float* W  = (z == 0) ? QW : (z == 1) ? KW : VW;
    const float* A  = (z == 0) ? QA : (z == 1) ? KA : VA;
    const float* Bm = (z == 0) ? QB : (z == 1) ? KB : VB;
    u16* Wb = WbAll + (size_t)z * NDIM * KDIM;

    __shared__ float As[16][64];
    const int t  = threadIdx.x;
    const int hb = blockIdx.x * 64;
    const int nb = blockIdx.y * 128;

    {   // stage A[16][hb:hb+64]
        int r = t >> 4, c = (t & 15) * 4;
        *(f32x4*)&As[r][c] = *(const f32x4*)&A[r * 4096 + hb + c];
    }
    __syncthreads();

    const int hl = (t & 7) * 8;
    const int n0 = nb + (t >> 3) * 4;

    float bv[4][16];
    float s[4][8];
#pragma unroll
    for (int i = 0; i < 4; i++) {
        const float* br = &Bm[(size_t)(n0 + i) * 16];
#pragma unroll
        for (int r = 0; r < 16; r++) bv[i][r] = 2.0f * br[r];
        f32x4 w0 = *(const f32x4*)&W[(size_t)(n0 + i) * 4096 + hb + hl];
        f32x4 w1 = *(const f32x4*)&W[(size_t)(n0 + i) * 4096 + hb + hl + 4];
        s[i][0] = w0[0]; s[i][1] = w0[1]; s[i][2] = w0[2]; s[i][3] = w0[3];
        s[i][4] = w1[0]; s[i][5] = w1[1]; s[i][6] = w1[2]; s[i][7] = w1[3];
    }
#pragma unroll
    for (int r = 0; r < 16; r++) {
        f32x4 a0 = *(const f32x4*)&As[r][hl];
        f32x4 a1 = *(const f32x4*)&As[r][hl + 4];
#pragma unroll
        for (int i = 0; i < 4; i++) {
            s[i][0] += bv[i][r] * a0[0]; s[i][1] += bv[i][r] * a0[1];
            s[i][2] += bv[i][r] * a0[2]; s[i][3] += bv[i][r] * a0[3];
            s[i][4] += bv[i][r] * a1[0]; s[i][5] += bv[i][r] * a1[1];
            s[i][6] += bv[i][r] * a1[2]; s[i][7] += bv[i][r] * a1[3];
        }
    }
#pragma unroll
    for (int i = 0; i < 4; i++) {
        s16x8 o;
#pragma unroll
        for (int j = 0; j < 8; j++) o[j] = (short)f2bf(s[i][j]);
        *(s16x8*)&Wb[(size_t)(n0 + i) * 4096 + hb + hl] = o;
    }
}

// ---------------- Kernel 3: 256x128 GEMM, BK=32, 4 waves, 2 blocks/CU ----------------
// 4 waves (2M x 2N), per-wave 128x64 out, acc[8][4] f32x4.
// LDS 48 KiB: A[2][256][32] (16K each) + B[2][128][32] (8K each) bf16.
// Swizzle (16B chunks, 4/row, R14/R15-verified): LDS(row,c)=glob(row,c^((row>>1)&3)).
//   Read: chunk = lkq ^ ((lr>>1)&3); bank: 2-way = free (m136).
//   Stage: row = i*64 + w*16 + (lane>>2); src chunk = (lane&3)^((lane>>3)&3).
// Phase (ONE raw barrier per K-tile T, parity p = T&1):
//   BAR; 12 reads (bufs p); STG A(T+1)(4) + B(T+1)(2) -> bufs p^1;
//   32 MFMA; vmcnt(0)
// WAR: bufs p^1 last read in phase T-1, lgkm-consumed by MFMA before that
// wave's BAR(T); stage after BAR(T). vmcnt(0) drains own stages pre-BAR.

#define BM 256
#define BN 128

#define BAR() asm volatile("s_barrier" ::: "memory")
#define WAIT_VM(n) asm volatile("s_waitcnt vmcnt(" #n ")" ::: "memory")
#define PRIO(p) __builtin_amdgcn_s_setprio(p)

__global__ void __launch_bounds__(256, 2) gemm8_kernel(const u16* __restrict__ Xb,
                                                       const u16* __restrict__ Wb,
                                                       float* __restrict__ out) {
    extern __shared__ char lds[];

    const int t    = threadIdx.x;
    const int lane = t & 63;
    const int w    = t >> 6;      // wave 0..3
    const int wr   = w >> 1;      // M wave 0..1
    const int wn   = w & 1;       // N wave 0..1
    const int lr   = lane & 15;
    const int lkq  = lane >> 4;

    // Z-sequential XCD-bijective remap: z = orig/1024 bands; within z:
    // i = (r&7)*128 + r/8 (bijective, 1024 = 8 x 128).
    const int orig = blockIdx.x;
    const int z    = orig >> 10;
    const int r0   = orig & 1023;
    const int i_   = (r0 & 7) * 128 + (r0 >> 3);
    const int nT = i_ & 31;                 // 32 n-tiles (4096/128)
    const int mT = i_ >> 5;                 // 32 m-tiles (8192/256)
    const int mBase = mT * BM;
    const int nBase = nT * BN;

    const u16* Wp = Wb + (size_t)z * NDIM * KDIM;
    const char* gA = (const char*)Xb + (size_t)mBase * (KDIM * 2);
    const char* gB = (const char*)Wp + (size_t)nBase * (KDIM * 2);

    char* ldsA0 = lds;              // 16 KiB
    char* ldsA1 = lds + 16384;      // 16 KiB
    char* ldsB0 = lds + 32768;      //  8 KiB
    char* ldsB1 = lds + 40960;      //  8 KiB

    // staging geometry: per instr i, thread covers chunk c = i*256 + w*64 + lane
    // row = c>>2 = i*64 + w*16 + (lane>>2); src col = (lane&3)^((lane>>3)&3)
    const int srcc = (((lane & 3) ^ ((lane >> 3) & 3)) << 4);
    const int rowL = w * 16 + (lane >> 2);
    const int ldsL = (w * 64 + lane) * 16;

#define STG_I(ldsT, g, kt, i)                                                     \
    __builtin_amdgcn_global_load_lds(                                             \
        (const __attribute__((address_space(1))) void*)((g) +                     \
            (size_t)((i) * 64 + rowL) * (KDIM * 2) + (size_t)(kt) * 64 + srcc),   \
        (__attribute__((address_space(3))) void*)((ldsT) + (i) * 4096 + ldsL),    \
        16, 0, 0);

#define STG_A(ldsT, kt) { STG_I(ldsT, gA, kt, 0) STG_I(ldsT, gA, kt, 1)           \
                          STG_I(ldsT, gA, kt, 2) STG_I(ldsT, gA, kt, 3) }
#define STG_B(ldsT, kt) { STG_I(ldsT, gB, kt, 0) STG_I(ldsT, gB, kt, 1) }

    // fragment reads: row byte stride 64; chunk = lkq ^ ((lr>>1)&3)
    const int csw = ((lkq ^ ((lr >> 1) & 3)) << 4);
    const int rA0 = (wr * 128 + lr) * 64;
    const int rB0 = (wn * 64 + lr) * 64;
#define RD_A(tile, mi) (*(const bf16x8*)((tile) + rA0 + (mi) * 1024 + csw))
#define RD_B(tile, ni) (*(const bf16x8*)((tile) + rB0 + (ni) * 1024 + csw))

    f32x4 acc[8][4] = {};
    bf16x8 a[8], b[4];

// one K-tile phase: BAR; 12 reads (consumption order); stage; 32 MFMA; vmcnt
#define PHASE(pA, pB, STG, VMW)                                                   \
  { BAR();                                                                        \
    a[0] = RD_A(pA, 0); b[0] = RD_B(pB, 0);                                       \
    a[1] = RD_A(pA, 1); b[1] = RD_B(pB, 1);                                       \
    a[2] = RD_A(pA, 2); b[2] = RD_B(pB, 2);                                       \
    a[3] = RD_A(pA, 3); b[3] = RD_B(pB, 3);                                       \
    a[4] = RD_A(pA, 4); a[5] = RD_A(pA, 5);                                       \
    a[6] = RD_A(pA, 6); a[7] = RD_A(pA, 7);                                       \
    STG;                                                                          \
    PRIO(1);                                                                      \
    _Pragma("unroll") for (int mi = 0; mi < 8; ++mi)                              \
    _Pragma("unroll") for (int ni = 0; ni < 4; ++ni)                              \
      acc[mi][ni] = __builtin_amdgcn_mfma_f32_16x16x32_bf16(                      \
          a[mi], b[ni], acc[mi][ni], 0, 0, 0);                                    \
    PRIO(0); VMW; }

    // ---- prologue: stage tile 0 ----
    STG_A(ldsA0, 0) STG_B(ldsB0, 0)
    WAIT_VM(0);

    // ---- main loop: 63 iterations (tiles T=2i, 2i+1); stages 1..126 ----
    for (int i = 0; i < 63; ++i) {
        const int T = 2 * i;
        PHASE(ldsA0, ldsB0, { STG_A(ldsA1, T + 1) STG_B(ldsB1, T + 1) },
              WAIT_VM(0));
        PHASE(ldsA1, ldsB1, { STG_A(ldsA0, T + 2) STG_B(ldsB0, T + 2) },
              WAIT_VM(0));
    }
    // ---- peeled tiles 126, 127 ----
    PHASE(ldsA0, ldsB0, { STG_A(ldsA1, 127) STG_B(ldsB1, 127) }, WAIT_VM(0));
    PHASE(ldsA1, ldsB1, , );

    // ---- epilogue: LDS-transpose ([64][128] f32 = 32 KiB) + full-line nt stores ----
    // __syncthreads() (NOT raw s_barrier): the acc->LDS ds_writes have no
    // in-wave consumer, so only the full s_waitcnt emitted by __syncthreads
    // guarantees they land before other waves read (R15 race fix).
    __syncthreads();
    float* C    = out + (size_t)z * MDIM * NDIM;
    float* ldsf = (float*)lds;
#pragma unroll
    for (int r = 0; r < 4; ++r) {
        if (wr == (r >> 1)) {
            // dump rows [r*64, r*64+64): acc mi-block (r&1)*4 .. +4
#pragma unroll
            for (int m2 = 0; m2 < 4; ++m2) {
                const int mi = (r & 1) * 4 + m2;
#pragma unroll
                for (int ni = 0; ni < 4; ++ni) {
                    const int lrow = m2 * 16 + lkq * 4;
                    const int col  = wn * 64 + ni * 16 + lr;
                    f32x4 v = acc[mi][ni];
#pragma unroll
                    for (int j = 0; j < 4; ++j)
                        ldsf[(lrow + j) * 128 + col] = v[j];
                }
            }
        }
        __syncthreads();
        // all 4 waves: 16 rows each; 64 lanes = 2 rows x 512B contiguous
        const size_t gb = (size_t)(mBase + r * 64) * NDIM + nBase;
#pragma unroll
        for (int rr = 0; rr < 8; ++rr) {
            const int row  = w * 16 + rr * 2 + (lane >> 5);
            const int colf = (lane & 31) * 4;
            f32x4 v = *(const f32x4*)&ldsf[row * 128 + colf];
            __builtin_nontemporal_store(v,
                (f32x4*)(C + gb + (size_t)row * NDIM + colf));
        }
        __syncthreads();   // before next round overwrites LDS
    }
}

// ---------------- host launch ----------------
extern "C" void kernel_launch(void* const* d_in, const int* in_sizes, int n_in,
                              void* d_out, int out_size, void* d_ws, size_t ws_size,
                              hipStream_t stream) {
    const float* X  = (const float*)d_in[0];
    const float* QW = (const float*)d_in[1];
    const float* QA = (const float*)d_in[2];
    const float* QB = (const float*)d_in[3];
    const float* KW = (const float*)d_in[4];
    const float* KA = (const float*)d_in[5];
    const float* KB = (const float*)d_in[6];
    const float* VW = (const float*)d_in[7];
    const float* VA = (const float*)d_in[8];
    const float* VB = (const float*)d_in[9];
    float* out = (float*)d_out;

    u16* Xb = (u16*)d_ws;                                        // 64 MiB
    u16* Wb = (u16*)((char*)d_ws + (size_t)MDIM * KDIM * 2);     // 3 x 32 MiB

    (void)hipFuncSetAttribute((const void*)gemm8_kernel,
                              hipFuncAttributeMaxDynamicSharedMemorySize, 49152);

    cvt_x_kernel<<<2048, 256, 0, stream>>>(X, Xb, (MDIM * KDIM) / 8);

    dim3 wgrid(4096 / 64, 4096 / 128, 3);
    merge_w3_kernel<<<wgrid, 256, 0, stream>>>(QW, QA, QB, KW, KA, KB, VW, VA, VB, Wb);

    gemm8_kernel<<<dim3(32 * 32 * 3), dim3(256), 49152, stream>>>(Xb, Wb, out);
}

// Round 17
// 738.058 us; speedup vs baseline: 12.8746x; 1.1986x over previous
//
#include <hip/hip_runtime.h>

// FusedLoRAQKV on MI355X (gfx950).
// Y_p = X @ (W_p + 2 * B_p @ A_p)^T  for p in {Q,K,V}
//
// Pipeline:
//   1. prep:  ONE launch = { merge_w3 (blocks 0..6143): W'=bf16(W+2*B@A);
//             cvt_x (blocks 6144..8191, grid-stride): X fp32->bf16 }.
//             Both HBM-bound and independent -> concurrent saves ~25us.
//   2. gemm:  R13 structure (best of 16 rounds): 256x256 tile, BK=64,
//             8 waves, mfma_f32_16x16x32_bf16, XOR-swizzled LDS (0
//             conflicts), single-barrier phases {BAR; reads; stage; MFMA},
//             12/8/4/0 reads, vmcnt(4)@P4/vmcnt(6)@P8, z-seq XCD remap,
//             LDS-transposed epilogue with full-line nt stores.
//             EPILOGUE RACE FIX vs R13: __syncthreads() (not raw s_barrier)
//             around the acc->LDS dump -- ds_writes have no in-wave
//             consumer, so raw s_barrier has no preceding lgkm wait
//             (fired at R15's 2-blocks/CU; latent at 1 block/CU).
//
// Closed paths (measured): schedule ordering R6-R10 flat; 32x32 MFMA has a
// fixed +4cyc/b128 LDS penalty (R3/R11/R12, swizzle-invariant); 2 blocks/CU
// regressed (R16: MfmaUtil 60->49).

typedef unsigned short u16;
typedef __attribute__((ext_vector_type(4))) float  f32x4;
typedef __attribute__((ext_vector_type(8))) __bf16 bf16x8;
typedef __attribute__((ext_vector_type(8))) short  s16x8;

#define MDIM 8192
#define NDIM 4096
#define KDIM 4096

__device__ __forceinline__ u16 f2bf(float f) {
    union { float f; unsigned int u; } v;
    v.f = f;
    unsigned int r = v.u + 0x7FFFu + ((v.u >> 16) & 1u);  // RNE
    return (u16)(r >> 16);
}

// ---------------- Kernel 1: fused prep (merge_w3 + cvt_x) ----------------
// blocks [0, 6144): merge -- bid -> z = bid/2048, by = (bid%2048)/64,
//                   bx = bid%64; W' tile 128 n-rows x 64 h-cols.
// blocks [6144, 8192): cvt -- 2048 blocks grid-stride over X (4M vec8).
__global__ void __launch_bounds__(256) prep_kernel(const float* __restrict__ X,
                                                   const float* __restrict__ QW,
                                                   const float* __restrict__ QA,
                                                   const float* __restrict__ QB,
                                                   const float* __restrict__ KW,
                                                   const float* __restrict__ KA,
                                                   const float* __restrict__ KB,
                                                   const float* __restrict__ VW,
                                                   const float* __restrict__ VA,
                                                   const float* __restrict__ VB,
                                                   u16* __restrict__ Xb,
                                                   u16* __restrict__ WbAll) {
    const int bid = blockIdx.x;
    const int t   = threadIdx.x;

    if (bid >= 6144) {
        // ---- cvt_x: X fp32 -> bf16, grid-stride ----
        const int nvec8  = (MDIM * KDIM) / 8;
        const int stride = 2048 * 256;
        for (int i = (bid - 6144) * 256 + t; i < nvec8; i += stride) {
            f32x4 x0 = ((const f32x4*)X)[2 * i];
            f32x4 x1 = ((const f32x4*)X)[2 * i + 1];
            s16x8 o;
            o[0] = (short)f2bf(x0[0]); o[1] = (short)f2bf(x0[1]);
            o[2] = (short)f2bf(x0[2]); o[3] = (short)f2bf(x0[3]);
            o[4] = (short)f2bf(x1[0]); o[5] = (short)f2bf(x1[1]);
            o[6] = (short)f2bf(x1[2]); o[7] = (short)f2bf(x1[3]);
            ((s16x8*)Xb)[i] = o;
        }
        return;
    }

    // ---- merge_w3 ----
    const int z   = bid >> 11;            // /2048
    const int rem = bid & 2047;
    const int hb  = (rem & 63) * 64;      // bx*64
    const int nb  = (rem >> 6) * 128;     // by*128
    const float* W  = (z == 0) ? QW : (z == 1) ? KW : VW;
    const float* A  = (z == 0) ? QA : (z == 1) ? KA : VA;
    const float* Bm = (z == 0) ? QB : (z == 1) ? KB : VB;
    u16* Wb = WbAll + (size_t)z * NDIM * KDIM;

    __shared__ float As[16][64];
    {   // stage A[16][hb:hb+64]
        int r = t >> 4, c = (t & 15) * 4;
        *(f32x4*)&As[r][c] = *(const f32x4*)&A[r * 4096 + hb + c];
    }
    __syncthreads();

    const int hl = (t & 7) * 8;
    const int n0 = nb + (t >> 3) * 4;

    float bv[4][16];
    float s[4][8];
#pragma unroll
    for (int i = 0; i < 4; i++) {
        const float* br = &Bm[(size_t)(n0 + i) * 16];
#pragma unroll
        for (int r = 0; r < 16; r++) bv[i][r] = 2.0f * br[r];
        f32x4 w0 = *(const f32x4*)&W[(size_t)(n0 + i) * 4096 + hb + hl];
        f32x4 w1 = *(const f32x4*)&W[(size_t)(n0 + i) * 4096 + hb + hl + 4];
        s[i][0] = w0[0]; s[i][1] = w0[1]; s[i][2] = w0[2]; s[i][3] = w0[3];
        s[i][4] = w1[0]; s[i][5] = w1[1]; s[i][6] = w1[2]; s[i][7] = w1[3];
    }
#pragma unroll
    for (int r = 0; r < 16; r++) {
        f32x4 a0 = *(const f32x4*)&As[r][hl];
        f32x4 a1 = *(const f32x4*)&As[r][hl + 4];
#pragma unroll
        for (int i = 0; i < 4; i++) {
            s[i][0] += bv[i][r] * a0[0]; s[i][1] += bv[i][r] * a0[1];
            s[i][2] += bv[i][r] * a0[2]; s[i][3] += bv[i][r] * a0[3];
            s[i][4] += bv[i][r] * a1[0]; s[i][5] += bv[i][r] * a1[1];
            s[i][6] += bv[i][r] * a1[2]; s[i][7] += bv[i][r] * a1[3];
        }
    }
#pragma unroll
    for (int i = 0; i < 4; i++) {
        s16x8 o;
#pragma unroll
        for (int j = 0; j < 8; j++) o[j] = (short)f2bf(s[i][j]);
        *(s16x8*)&Wb[(size_t)(n0 + i) * 4096 + hb + hl] = o;
    }
}

// ---------------- Kernel 2: 256x256 single-barrier-phase GEMM (R13) ----------------
// 8 waves (2M x 4N), per-wave 128x64 out, acc[8][4] f32x4 (16x16x32 MFMA).
// LDS 128 KiB: A[2][256][64] + B[2][256][64] bf16, 16B-chunk XOR swizzle
// (chunk ^= row&7), linear-dst global_load_lds + pre-swizzled source.
//
// Phase = { BAR ; ds_reads ; stage ; [vmcnt] ; MFMA }.  ONE barrier/phase.
//   P1: rd 12 (aR1, bR01); STG; Q1   P2: rd 8 (b23, aR2a); STG; Q2
//   P3: rd 4  (aR2b);      STG; Q3   P4: STG; vmcnt; Q4
// WAR/vmcnt audits (R7/R8-verified): A-buf staged P5/P6 (last read P3);
// B-buf staged P3/P4 (last read P2); carry into P1 = 6; P4: vmcnt(4);
// P8: vmcnt(6). K-loop raw BARs safe: every ds_read is lgkm-consumed by an
// MFMA before its wave reaches the next BAR; stages vmcnt-drained pre-BAR.

#define BM 256
#define BN 256
#define BK 64

#define BAR() asm volatile("s_barrier" ::: "memory")
#define WAIT_VM(n) asm volatile("s_waitcnt vmcnt(" #n ")" ::: "memory")
#define PRIO(p) __builtin_amdgcn_s_setprio(p)

__global__ void __launch_bounds__(512, 2) gemm8_kernel(const u16* __restrict__ Xb,
                                                       const u16* __restrict__ Wb,
                                                       float* __restrict__ out) {
    extern __shared__ char lds[];

    const int t    = threadIdx.x;
    const int lane = t & 63;
    const int w    = t >> 6;      // wave 0..7
    const int wr   = w >> 2;      // M wave 0..1
    const int wn   = w & 3;       // N wave 0..3
    const int lr   = lane & 15;
    const int lkq  = lane >> 4;
    const int lr7  = lr & 7;

    // Z-sequential XCD-bijective remap (R8): z = orig/512 sequential bands;
    // within z: i = (r&7)*64 + r/8 (bijective, 512 = 8 x 64).
    const int orig = blockIdx.x;
    const int z    = orig >> 9;
    const int r0   = orig & 511;
    const int i_   = (r0 & 7) * 64 + (r0 >> 3);
    const int nT = i_ & 15;
    const int mT = i_ >> 4;
    const int mBase = mT * BM;
    const int nBase = nT * BN;

    const u16* Wp = Wb + (size_t)z * NDIM * KDIM;
    const char* gA = (const char*)Xb + (size_t)mBase * (KDIM * 2);
    const char* gB = (const char*)Wp + (size_t)nBase * (KDIM * 2);

    char* ldsA0 = lds;
    char* ldsA1 = lds + 32768;
    char* ldsB0 = lds + 65536;
    char* ldsB1 = lds + 98304;

    // staging: 2 x global_load_lds(16B)/wave/half-tile, linear LDS dst,
    // pre-swizzled global source column (involution, rule 21)
    const int blkrow = lane >> 3;
    const int colswz = ((lane & 7) ^ blkrow) << 4;
    const size_t stg0 = (size_t)(((w << 1) | 0) * 8 + blkrow) * (KDIM * 2) + colswz;
    const size_t stg1 = (size_t)(((w << 1) | 1) * 8 + blkrow) * (KDIM * 2) + colswz;
    const int ldsStg0 = (((w << 1) | 0) << 10) + lane * 16;
    const int ldsStg1 = (((w << 1) | 1) << 10) + lane * 16;

#define STAGE(ldsTile, gtile, h, kt)                                              \
  { __builtin_amdgcn_global_load_lds(                                             \
        (const __attribute__((address_space(1))) void*)((gtile) + stg0 +          \
            (size_t)(h) * (128 * KDIM * 2) + (size_t)(kt) * 128),                 \
        (__attribute__((address_space(3))) void*)((ldsTile) + (h) * 16384 + ldsStg0), \
        16, 0, 0);                                                                \
    __builtin_amdgcn_global_load_lds(                                             \
        (const __attribute__((address_space(1))) void*)((gtile) + stg1 +          \
            (size_t)(h) * (128 * KDIM * 2) + (size_t)(kt) * 128),                 \
        (__attribute__((address_space(3))) void*)((ldsTile) + (h) * 16384 + ldsStg1), \
        16, 0, 0); }

    // ds_read: row*128 + (((kk<<2)|lkq) ^ (row&7))*16 ; row&7 == lr7
    const int csA = (lkq << 4) ^ (lr7 << 4);
    const int rA0 = (wr * 128 + lr) * 128;
    const int rB0 = (wn * 64 + lr) * 128;
#define RD_A(tile, mi, kk) (*(const bf16x8*)((tile) + rA0 + (mi) * 2048 + (((kk) << 6) ^ csA)))
#define RD_B(tile, ni, kk) (*(const bf16x8*)((tile) + rB0 + (ni) * 2048 + (((kk) << 6) ^ csA)))

    f32x4 acc[8][4] = {};
    bf16x8 aR1[4][2], aR2[4][2], bR[4][2];

#define MFMA_Q(AF, mbase, nbase)                                                   \
    PRIO(1);                                                                       \
    _Pragma("unroll") for (int mi = 0; mi < 4; ++mi)                               \
    _Pragma("unroll") for (int ni = 0; ni < 2; ++ni)                               \
    _Pragma("unroll") for (int kk = 0; kk < 2; ++kk)                               \
      acc[(mbase) + mi][(nbase) + ni] = __builtin_amdgcn_mfma_f32_16x16x32_bf16(   \
          AF[mi][kk], bR[(nbase) + ni][kk], acc[(mbase) + mi][(nbase) + ni], 0, 0, 0); \
    PRIO(0);

#define PH1(pA, pB, STG)                                                           \
  { BAR();                                                                         \
    aR1[0][0] = RD_A(pA, 0, 0); aR1[0][1] = RD_A(pA, 0, 1);                        \
    bR[0][0]  = RD_B(pB, 0, 0); bR[0][1]  = RD_B(pB, 0, 1);                        \
    aR1[1][0] = RD_A(pA, 1, 0); aR1[1][1] = RD_A(pA, 1, 1);                        \
    bR[1][0]  = RD_B(pB, 1, 0); bR[1][1]  = RD_B(pB, 1, 1);                        \
    aR1[2][0] = RD_A(pA, 2, 0); aR1[2][1] = RD_A(pA, 2, 1);                        \
    aR1[3][0] = RD_A(pA, 3, 0); aR1[3][1] = RD_A(pA, 3, 1);                        \
    STG; MFMA_Q(aR1, 0, 0) }

#define PH2(pA, pB, STG)                                                           \
  { BAR();                                                                         \
    bR[2][0] = RD_B(pB, 2, 0); bR[2][1] = RD_B(pB, 2, 1);                          \
    bR[3][0] = RD_B(pB, 3, 0); bR[3][1] = RD_B(pB, 3, 1);                          \
    aR2[0][0] = RD_A(pA, 4, 0); aR2[0][1] = RD_A(pA, 4, 1);                        \
    aR2[1][0] = RD_A(pA, 5, 0); aR2[1][1] = RD_A(pA, 5, 1);                        \
    STG; MFMA_Q(aR1, 0, 2) }

#define PH3(pA, STG)                                                               \
  { BAR();                                                                         \
    aR2[2][0] = RD_A(pA, 6, 0); aR2[2][1] = RD_A(pA, 6, 1);                        \
    aR2[3][0] = RD_A(pA, 7, 0); aR2[3][1] = RD_A(pA, 7, 1);                        \
    STG; MFMA_Q(aR2, 4, 0) }

#define PH4(STG, VMW)                                                              \
  { BAR(); STG; VMW; MFMA_Q(aR2, 4, 2) }

#define PH4F()                                                                     \
  { BAR(); MFMA_Q(aR2, 4, 2) }

    // ---- prologue: A(0) full, B(0) full, B(1) full, A(1).Ah0 = 14 loads ----
    STAGE(ldsA0, gA, 0, 0); STAGE(ldsA0, gA, 1, 0);
    STAGE(ldsB0, gB, 0, 0); STAGE(ldsB0, gB, 1, 0);
    STAGE(ldsB1, gB, 0, 1); STAGE(ldsB1, gB, 1, 1);
    STAGE(ldsA1, gA, 0, 1);
    WAIT_VM(6);   // drain A(0)+B(0); leftover 6 = B(1)+A(1).Ah0 = steady carry

    // ---- main loop: 31 iterations (tiles T=2i, T+1), T = 0..60 ----
    for (int i = 0; i < 31; ++i) {
        const int T = 2 * i;
        PH1(ldsA0, ldsB0, STAGE(ldsA1, gA, 1, T + 1));                   // A(T+1).Ah1
        PH2(ldsA0, ldsB0, );                                             // no stage
        PH3(ldsA0,        STAGE(ldsB0, gB, 0, T + 2));                   // B(T+2).Bh0
        PH4(              STAGE(ldsB0, gB, 1, T + 2), WAIT_VM(4));       // B(T+2).Bh1
        PH1(ldsA1, ldsB1, STAGE(ldsA0, gA, 0, T + 2));                   // A(T+2).Ah0
        PH2(ldsA1, ldsB1, STAGE(ldsA0, gA, 1, T + 2));                   // A(T+2).Ah1
        PH3(ldsA1,        STAGE(ldsB1, gB, 0, T + 3));                   // B(T+3).Bh0
        PH4(              { STAGE(ldsB1, gB, 1, T + 3)                   // B(T+3).Bh1
                            STAGE(ldsA1, gA, 0, T + 3) }, WAIT_VM(6));   // A(T+3).Ah0
    }

    // ---- peeled last pair (tiles 62, 63) ----
    PH1(ldsA0, ldsB0, STAGE(ldsA1, gA, 1, 63));                          // A(63).Ah1
    PH2(ldsA0, ldsB0, );
    PH3(ldsA0, );
    PH4(, WAIT_VM(0));                                                   // all landed
    PH1(ldsA1, ldsB1, );
    PH2(ldsA1, ldsB1, );
    PH3(ldsA1, );
    PH4F();

    // ---- epilogue: LDS-transpose + full-line nontemporal stores ----
    // __syncthreads() (NOT raw s_barrier): acc->LDS ds_writes have no
    // in-wave consumer -> raw barrier has no preceding lgkm wait (R15 race).
    __syncthreads();
    float* C    = out + (size_t)z * MDIM * NDIM;
    float* ldsf = (float*)lds;                    // f32 [128][256] = 128 KiB
#pragma unroll
    for (int round = 0; round < 2; ++round) {
        if (wr == round) {
            // dump acc into LDS in C layout (rows relative to wr*128)
#pragma unroll
            for (int mi = 0; mi < 8; ++mi) {
#pragma unroll
                for (int ni = 0; ni < 4; ++ni) {
                    const int lrow = mi * 16 + lkq * 4;
                    const int col  = wn * 64 + ni * 16 + lr;
                    f32x4 v = acc[mi][ni];
#pragma unroll
                    for (int j = 0; j < 4; ++j)
                        ldsf[(lrow + j) * 256 + col] = v[j];
                }
            }
        }
        __syncthreads();
        // all 8 waves: store 16 rows each; 64 lanes x f32x4 = 1KB/row segment
        const size_t gb = (size_t)(mBase + round * 128) * NDIM + nBase;
#pragma unroll
        for (int rr = 0; rr < 16; ++rr) {
            const int row = w * 16 + rr;
            f32x4 v = *(const f32x4*)&ldsf[row * 256 + lane * 4];
            __builtin_nontemporal_store(v,
                (f32x4*)(C + gb + (size_t)row * NDIM + lane * 4));
        }
        __syncthreads();   // before next round overwrites LDS
    }
}

// ---------------- host launch ----------------
extern "C" void kernel_launch(void* const* d_in, const int* in_sizes, int n_in,
                              void* d_out, int out_size, void* d_ws, size_t ws_size,
                              hipStream_t stream) {
    const float* X  = (const float*)d_in[0];
    const float* QW = (const float*)d_in[1];
    const float* QA = (const float*)d_in[2];
    const float* QB = (const float*)d_in[3];
    const float* KW = (const float*)d_in[4];
    const float* KA = (const float*)d_in[5];
    const float* KB = (const float*)d_in[6];
    const float* VW = (const float*)d_in[7];
    const float* VA = (const float*)d_in[8];
    const float* VB = (const float*)d_in[9];
    float* out = (float*)d_out;

    u16* Xb = (u16*)d_ws;                                        // 64 MiB
    u16* Wb = (u16*)((char*)d_ws + (size_t)MDIM * KDIM * 2);     // 3 x 32 MiB

    (void)hipFuncSetAttribute((const void*)gemm8_kernel,
                              hipFuncAttributeMaxDynamicSharedMemorySize, 131072);

    prep_kernel<<<8192, 256, 0, stream>>>(X, QW, QA, QB, KW, KA, KB,
                                          VW, VA, VB, Xb, Wb);

    gemm8_kernel<<<dim3(16 * 32 * 3), dim3(512), 131072, stream>>>(Xb, Wb, out);
}